// Round 3
// baseline (1182.510 us; speedup 1.0000x reference)
//
#include <hip/hip_runtime.h>
#include <hip/hip_bf16.h>
#include <math.h>

#define T_LEN 827
#define M_ROWS 3308   // B*T
#define NLAYER 12

typedef __attribute__((ext_vector_type(4))) float f32x4;
typedef __attribute__((ext_vector_type(8))) short bf16x8;

__device__ __forceinline__ float gelu_f(float x) {
    return 0.5f * x * (1.0f + erff(x * 0.70710678118654752440f));
}

__device__ __forceinline__ short f2bf_s(float x) {
    __hip_bfloat16 h = __float2bfloat16(x);
    return *reinterpret_cast<short*>(&h);
}

// ---------------- f32 -> bf16 conversion ----------------
__global__ void cvt_kernel(const float* __restrict__ in, __hip_bfloat16* __restrict__ out, int n4) {
    int i = blockIdx.x * blockDim.x + threadIdx.x;
    if (i >= n4) return;
    float4 v = reinterpret_cast<const float4*>(in)[i];
    out[4*i+0] = __float2bfloat16(v.x);
    out[4*i+1] = __float2bfloat16(v.y);
    out[4*i+2] = __float2bfloat16(v.z);
    out[4*i+3] = __float2bfloat16(v.w);
}

// Build stacked QKV weights (12, 768, 256) bf16 with qscale folded into Wq rows.
__global__ void prep_wqkv_kernel(const float* __restrict__ Wq, const float* __restrict__ Wk,
                                 const float* __restrict__ Wv, __hip_bfloat16* __restrict__ out) {
    int i = blockIdx.x * 256 + threadIdx.x;
    if (i >= 12*768*64) return;
    int el = i * 4;
    int layer = el / (768*256);
    int rem = el % (768*256);
    int row = rem >> 8, col = rem & 255;
    const float* src;
    float sc = 1.f;
    if (row < 256)      { src = Wq + ((size_t)layer*256 + row)*256 + col; sc = 0.17677669529663687f; }
    else if (row < 512) { src = Wk + ((size_t)layer*256 + (row-256))*256 + col; }
    else                { src = Wv + ((size_t)layer*256 + (row-512))*256 + col; }
    float4 v = *reinterpret_cast<const float4*>(src);
    out[el+0] = __float2bfloat16(v.x * sc);
    out[el+1] = __float2bfloat16(v.y * sc);
    out[el+2] = __float2bfloat16(v.z * sc);
    out[el+3] = __float2bfloat16(v.w * sc);
}

__global__ void prep_bqkv_kernel(const float* __restrict__ bq, const float* __restrict__ bk,
                                 const float* __restrict__ bv, float* __restrict__ out) {
    int i = blockIdx.x * 256 + threadIdx.x;
    if (i >= 12*768) return;
    int layer = i / 768, row = i % 768;
    float v;
    if (row < 256)      v = bq[layer*256 + row] * 0.17677669529663687f;
    else if (row < 512) v = bk[layer*256 + (row-256)];
    else                v = bv[layer*256 + (row-512)];
    out[i] = v;
}

__global__ void zero_kernel(float* __restrict__ p, int n) {
    for (int i = blockIdx.x * blockDim.x + threadIdx.x; i < n; i += gridDim.x * blockDim.x)
        p[i] = 0.f;
}

// ---------------- locality ----------------
__global__ void loc_z1_kernel(const float* __restrict__ p1, const float* __restrict__ p2,
                              const float* __restrict__ p3, const float* __restrict__ W1,
                              const float* __restrict__ b1, float* __restrict__ z1) {
    for (int i = threadIdx.x; i < 720; i += 256) {
        int pi = i / 240, rem = i % 240, b = rem / 60, j = rem % 60;
        const float* p = (pi == 0) ? p1 : ((pi == 1) ? p2 : p3);
        float acc = b1[j];
        #pragma unroll
        for (int c = 0; c < 30; ++c) acc += p[b*30 + c] * W1[j*30 + c];
        z1[i] = gelu_f(acc);
    }
}

__global__ void h_fill_kernel(const float* __restrict__ z1, const float* __restrict__ W2,
                              const float* __restrict__ b2, float* __restrict__ h) {
    __shared__ float z[720];
    int tid = threadIdx.x;
    for (int i = tid; i < 720; i += 256) z[i] = z1[i];
    __syncthreads();
    int j = blockIdx.x * 256 + tid;
    float w[60];
    #pragma unroll
    for (int c = 0; c < 60; ++c) w[c] = W2[(size_t)j*60 + c];
    float bj = b2[j];
    int r = j >> 8, cc = j & 255;
    const int br[3] = {285, 571, 571};
    const int bc[3] = {0, 0, 286};
    #pragma unroll
    for (int pi = 0; pi < 3; ++pi) {
        for (int b = 0; b < 4; ++b) {
            float acc = bj;
            #pragma unroll
            for (int c = 0; c < 60; ++c) acc += z[pi*240 + b*60 + c] * w[c];
            h[(size_t)b*T_LEN*T_LEN + (size_t)(br[pi] + r)*T_LEN + bc[pi] + cc] = acc;
        }
    }
}

// ---------------- x = tok + role + time ----------------
__global__ void init_x_kernel(const float* __restrict__ dc, const float* __restrict__ z,
                              const float* __restrict__ frame, const float* __restrict__ cam,
                              const float* __restrict__ timeE, float* __restrict__ x) {
    int idx = blockIdx.x * 256 + threadIdx.x;
    int m = idx >> 8, c = idx & 255;
    int b = m / T_LEN, t = m % T_LEN;
    float tok = (t < 572) ? dc[((size_t)b*572 + t)*256 + c]
                          : z[((size_t)b*256 + (t - 572))*256 + c];
    float role;
    if      (t < 256) role = frame[t*256 + c];
    else if (t < 286) role = cam[(t-256)*256 + c];
    else if (t < 542) role = frame[(t-286)*256 + c];
    else if (t < 572) role = cam[(t-542)*256 + c];
    else              role = frame[(t-572)*256 + c];
    x[idx] = tok + role + timeE[t*256 + c];
}

// ---------------- single-sync full-K-resident GEMM (K=256) ----------------
// out(MxN) = A_or_LN(x)(Mx256) @ W(Nx256)^T + bias [+resid].
// Tile 64x64, 4 waves (2x2), one sync between staging and 32 MFMAs.
template<bool LN, bool RESID, bool OUTBF16>
__global__ __launch_bounds__(256) void gemm_k256(
    const float* __restrict__ xsrc, const float* __restrict__ lnw, const float* __restrict__ lnb,
    const __hip_bfloat16* __restrict__ Abf,
    const __hip_bfloat16* __restrict__ W, const float* __restrict__ bias,
    const float* __restrict__ resid, void* __restrict__ out, int M, int N)
{
    __shared__ __hip_bfloat16 As[64][264];
    __shared__ __hip_bfloat16 Bs[64][264];
    __shared__ float redS[4][64], redQ[4][64];
    const int tid = threadIdx.x;
    const int m0 = blockIdx.x * 64, n0 = blockIdx.y * 64;
    const int r = tid >> 2, sg = tid & 3;

    // stage B tile (rows n0..n0+63; N is always a multiple of 64)
    {
        const __hip_bfloat16* bsrc = W + (size_t)(n0 + r) * 256 + sg * 8;
        #pragma unroll
        for (int j = 0; j < 8; ++j)
            *reinterpret_cast<uint4*>(&Bs[r][sg*8 + j*32]) =
                *reinterpret_cast<const uint4*>(bsrc + j*32);
    }
    int gr = m0 + r; if (gr > M-1) gr = M-1;
    if constexpr (LN) {
        const float* src = xsrc + (size_t)gr * 256;
        float s = 0.f, q = 0.f;
        #pragma unroll
        for (int j = 0; j < 8; ++j) {
            int k = sg*8 + j*32;
            float4 a = *reinterpret_cast<const float4*>(src + k);
            float4 c4 = *reinterpret_cast<const float4*>(src + k + 4);
            s += a.x + a.y + a.z + a.w + c4.x + c4.y + c4.z + c4.w;
            q += a.x*a.x + a.y*a.y + a.z*a.z + a.w*a.w
               + c4.x*c4.x + c4.y*c4.y + c4.z*c4.z + c4.w*c4.w;
        }
        redS[sg][r] = s; redQ[sg][r] = q;
        __syncthreads();
        float mean = (redS[0][r] + redS[1][r] + redS[2][r] + redS[3][r]) * (1.f/256.f);
        float msq  = (redQ[0][r] + redQ[1][r] + redQ[2][r] + redQ[3][r]) * (1.f/256.f);
        float rstd = rsqrtf(msq - mean*mean + 1e-5f);
        #pragma unroll
        for (int j = 0; j < 8; ++j) {
            int k = sg*8 + j*32;
            float4 a = *reinterpret_cast<const float4*>(src + k);
            float4 c4 = *reinterpret_cast<const float4*>(src + k + 4);
            float v[8] = {a.x, a.y, a.z, a.w, c4.x, c4.y, c4.z, c4.w};
            bf16x8 pk;
            #pragma unroll
            for (int e = 0; e < 8; ++e)
                pk[e] = f2bf_s((v[e] - mean) * rstd * lnw[k+e] + lnb[k+e]);
            *reinterpret_cast<bf16x8*>(&As[r][k]) = pk;
        }
    } else {
        const __hip_bfloat16* asrc = Abf + (size_t)gr * 256 + sg * 8;
        #pragma unroll
        for (int j = 0; j < 8; ++j)
            *reinterpret_cast<uint4*>(&As[r][sg*8 + j*32]) =
                *reinterpret_cast<const uint4*>(asrc + j*32);
    }
    __syncthreads();

    const int wid = tid >> 6, lane = tid & 63;
    const int wm = wid >> 1, wn = wid & 1, c = lane & 15, g = lane >> 4;
    f32x4 acc[2][2];
    #pragma unroll
    for (int mi = 0; mi < 2; ++mi)
        #pragma unroll
        for (int ni = 0; ni < 2; ++ni)
            acc[mi][ni] = (f32x4){0.f, 0.f, 0.f, 0.f};

    #pragma unroll
    for (int kj = 0; kj < 8; ++kj) {
        bf16x8 a0 = *reinterpret_cast<const bf16x8*>(&As[wm*32 + c][kj*32 + g*8]);
        bf16x8 a1 = *reinterpret_cast<const bf16x8*>(&As[wm*32 + 16 + c][kj*32 + g*8]);
        bf16x8 b0 = *reinterpret_cast<const bf16x8*>(&Bs[wn*32 + c][kj*32 + g*8]);
        bf16x8 b1v = *reinterpret_cast<const bf16x8*>(&Bs[wn*32 + 16 + c][kj*32 + g*8]);
        acc[0][0] = __builtin_amdgcn_mfma_f32_16x16x32_bf16(a0, b0, acc[0][0], 0, 0, 0);
        acc[0][1] = __builtin_amdgcn_mfma_f32_16x16x32_bf16(a0, b1v, acc[0][1], 0, 0, 0);
        acc[1][0] = __builtin_amdgcn_mfma_f32_16x16x32_bf16(a1, b0, acc[1][0], 0, 0, 0);
        acc[1][1] = __builtin_amdgcn_mfma_f32_16x16x32_bf16(a1, b1v, acc[1][1], 0, 0, 0);
    }

    #pragma unroll
    for (int mi = 0; mi < 2; ++mi) {
        #pragma unroll
        for (int ni = 0; ni < 2; ++ni) {
            int n = n0 + wn*32 + ni*16 + c;
            float bb = bias ? bias[n] : 0.f;
            #pragma unroll
            for (int rg = 0; rg < 4; ++rg) {
                int m = m0 + wm*32 + mi*16 + g*4 + rg;
                if (m >= M) continue;
                float v = acc[mi][ni][rg] + bb;
                if (RESID) v += resid[(size_t)m*N + n];
                if (OUTBF16) ((__hip_bfloat16*)out)[(size_t)m*N + n] = __float2bfloat16(v);
                else         ((float*)out)[(size_t)m*N + n] = v;
            }
        }
    }
}

// ---------------- fused MLP: LN2 + W1/gelu + W2 + residual (+ final LN) ----------------
// 32 rows/block, 512 threads (8 waves). mid (32x1024) in LDS; W1/W2 streamed from global.
template<bool FINAL>
__global__ __launch_bounds__(512) void mlp_fused(
    float* __restrict__ x,
    const float* __restrict__ ln2w, const float* __restrict__ ln2b,
    const __hip_bfloat16* __restrict__ W1, const float* __restrict__ b1,
    const __hip_bfloat16* __restrict__ W2, const float* __restrict__ b2,
    const float* __restrict__ lnfw, const float* __restrict__ lnfb,
    __hip_bfloat16* __restrict__ xn)
{
    __shared__ __hip_bfloat16 As[32][264];
    __shared__ __hip_bfloat16 Ms[32][1044];
    const int tid = threadIdx.x;
    const int m0 = blockIdx.x * 32;
    const int w = tid >> 6, lane = tid & 63, c = lane & 15, g = lane >> 4;

    // phase 0: LN2 of 32 rows (16 threads/row, shfl reduce within 16-lane groups)
    {
        int r = tid >> 4, p = tid & 15;
        int gr = m0 + r; if (gr > M_ROWS-1) gr = M_ROWS-1;
        const float* src = x + (size_t)gr*256 + p*16;
        float4 f0 = *reinterpret_cast<const float4*>(src);
        float4 f1 = *reinterpret_cast<const float4*>(src + 4);
        float4 f2 = *reinterpret_cast<const float4*>(src + 8);
        float4 f3 = *reinterpret_cast<const float4*>(src + 12);
        float vv[16] = {f0.x,f0.y,f0.z,f0.w, f1.x,f1.y,f1.z,f1.w,
                        f2.x,f2.y,f2.z,f2.w, f3.x,f3.y,f3.z,f3.w};
        float s = 0.f, q = 0.f;
        #pragma unroll
        for (int e = 0; e < 16; ++e) { s += vv[e]; q += vv[e]*vv[e]; }
        #pragma unroll
        for (int msk = 1; msk <= 8; msk <<= 1) { s += __shfl_xor(s, msk); q += __shfl_xor(q, msk); }
        float mean = s * (1.f/256.f);
        float rstd = rsqrtf(q*(1.f/256.f) - mean*mean + 1e-5f);
        bf16x8 pk0, pk1;
        #pragma unroll
        for (int e = 0; e < 8; ++e) {
            pk0[e] = f2bf_s((vv[e]   - mean)*rstd*ln2w[p*16+e]   + ln2b[p*16+e]);
            pk1[e] = f2bf_s((vv[8+e] - mean)*rstd*ln2w[p*16+8+e] + ln2b[p*16+8+e]);
        }
        *reinterpret_cast<bf16x8*>(&As[r][p*16])     = pk0;
        *reinterpret_cast<bf16x8*>(&As[r][p*16 + 8]) = pk1;
    }
    __syncthreads();

    // GEMM1 + gelu -> Ms. wave w owns n = w*128 .. w*128+127
    #pragma unroll 1
    for (int ns = 0; ns < 8; ++ns) {
        int nb = w*128 + ns*16;
        const __hip_bfloat16* wrow = W1 + (size_t)(nb + c)*256 + g*8;
        f32x4 a0 = (f32x4){0.f,0.f,0.f,0.f}, a1 = (f32x4){0.f,0.f,0.f,0.f};
        #pragma unroll
        for (int kj = 0; kj < 8; ++kj) {
            bf16x8 bfrag = *reinterpret_cast<const bf16x8*>(wrow + kj*32);
            bf16x8 af0 = *reinterpret_cast<const bf16x8*>(&As[c][kj*32 + g*8]);
            bf16x8 af1 = *reinterpret_cast<const bf16x8*>(&As[16 + c][kj*32 + g*8]);
            a0 = __builtin_amdgcn_mfma_f32_16x16x32_bf16(af0, bfrag, a0, 0, 0, 0);
            a1 = __builtin_amdgcn_mfma_f32_16x16x32_bf16(af1, bfrag, a1, 0, 0, 0);
        }
        float bb = b1[nb + c];
        #pragma unroll
        for (int rg = 0; rg < 4; ++rg) {
            Ms[g*4 + rg][nb + c]      = __float2bfloat16(gelu_f(a0[rg] + bb));
            Ms[16 + g*4 + rg][nb + c] = __float2bfloat16(gelu_f(a1[rg] + bb));
        }
    }
    __syncthreads();

    // GEMM2: wave w owns n = w*32 .. w*32+31, K=1024 from Ms
    f32x4 o[2][2];
    #pragma unroll
    for (int i = 0; i < 2; ++i)
        #pragma unroll
        for (int j = 0; j < 2; ++j)
            o[i][j] = (f32x4){0.f,0.f,0.f,0.f};
    #pragma unroll
    for (int ns2 = 0; ns2 < 2; ++ns2) {
        int nb = w*32 + ns2*16;
        const __hip_bfloat16* wrow = W2 + (size_t)(nb + c)*1024 + g*8;
        #pragma unroll
        for (int kj = 0; kj < 32; ++kj) {
            bf16x8 bfrag = *reinterpret_cast<const bf16x8*>(wrow + kj*32);
            bf16x8 af0 = *reinterpret_cast<const bf16x8*>(&Ms[c][kj*32 + g*8]);
            bf16x8 af1 = *reinterpret_cast<const bf16x8*>(&Ms[16 + c][kj*32 + g*8]);
            o[ns2][0] = __builtin_amdgcn_mfma_f32_16x16x32_bf16(af0, bfrag, o[ns2][0], 0, 0, 0);
            o[ns2][1] = __builtin_amdgcn_mfma_f32_16x16x32_bf16(af1, bfrag, o[ns2][1], 0, 0, 0);
        }
    }
    __syncthreads();   // all Ms reads complete (needed before FINAL xf overlay)

    float* xf = reinterpret_cast<float*>(&Ms[0][0]);
    #pragma unroll
    for (int ns2 = 0; ns2 < 2; ++ns2) {
        int nb = w*32 + ns2*16;
        float bb = b2[nb + c];
        #pragma unroll
        for (int mi = 0; mi < 2; ++mi) {
            #pragma unroll
            for (int rg = 0; rg < 4; ++rg) {
                int row = mi*16 + g*4 + rg;
                int gm = m0 + row;
                if (gm < M_ROWS) {
                    float v = o[ns2][mi][rg] + bb + x[(size_t)gm*256 + nb + c];
                    x[(size_t)gm*256 + nb + c] = v;
                    if (FINAL) xf[row*256 + nb + c] = v;
                }
            }
        }
    }

    if constexpr (FINAL) {
        __syncthreads();
        int r = tid >> 4, p = tid & 15;
        int gm = m0 + r;
        const float* src = xf + r*256 + p*16;
        float4 f0 = *reinterpret_cast<const float4*>(src);
        float4 f1 = *reinterpret_cast<const float4*>(src + 4);
        float4 f2 = *reinterpret_cast<const float4*>(src + 8);
        float4 f3 = *reinterpret_cast<const float4*>(src + 12);
        float vv[16] = {f0.x,f0.y,f0.z,f0.w, f1.x,f1.y,f1.z,f1.w,
                        f2.x,f2.y,f2.z,f2.w, f3.x,f3.y,f3.z,f3.w};
        float s = 0.f, q = 0.f;
        #pragma unroll
        for (int e = 0; e < 16; ++e) { s += vv[e]; q += vv[e]*vv[e]; }
        #pragma unroll
        for (int msk = 1; msk <= 8; msk <<= 1) { s += __shfl_xor(s, msk); q += __shfl_xor(q, msk); }
        float mean = s * (1.f/256.f);
        float rstd = rsqrtf(q*(1.f/256.f) - mean*mean + 1e-5f);
        if (gm < M_ROWS) {
            bf16x8 pk0, pk1;
            #pragma unroll
            for (int e = 0; e < 8; ++e) {
                pk0[e] = f2bf_s((vv[e]   - mean)*rstd*lnfw[p*16+e]   + lnfb[p*16+e]);
                pk1[e] = f2bf_s((vv[8+e] - mean)*rstd*lnfw[p*16+8+e] + lnfb[p*16+8+e]);
            }
            *reinterpret_cast<bf16x8*>(&xn[(size_t)gm*256 + p*16])     = pk0;
            *reinterpret_cast<bf16x8*>(&xn[(size_t)gm*256 + p*16 + 8]) = pk1;
        }
    }
}

// ---------------- MFMA flash attention (double-buffered staging) ----------------
template<int ADAPT>
__global__ __launch_bounds__(256) void attn_mfma_kernel(const __hip_bfloat16* __restrict__ qkv,
                                                        const float* __restrict__ hbuf,
                                                        __hip_bfloat16* __restrict__ y) {
    const int qi = blockIdx.x, hh = blockIdx.y, b = blockIdx.z;
    const int tid = threadIdx.x;
    const int w = tid >> 6, lane = tid & 63;
    const int c = lane & 15, g = lane >> 4;
    const int q0 = qi * 64;
    const int qw0 = q0 + w * 16;

    __shared__ short Ks[2][64][40];
    __shared__ short Vt[2][32][68];
    __shared__ short Pw[4][16][72];

    int qrow = qw0 + c; if (qrow > T_LEN-1) qrow = T_LEN-1;
    bf16x8 aq = *reinterpret_cast<const bf16x8*>(qkv + ((size_t)b*T_LEN + qrow)*768 + hh*32 + g*8);

    float m_r[4] = {-INFINITY, -INFINITY, -INFINITY, -INFINITY};
    float l_r[4] = {0.f, 0.f, 0.f, 0.f};
    f32x4 acc[2];
    acc[0] = (f32x4){0.f,0.f,0.f,0.f};
    acc[1] = (f32x4){0.f,0.f,0.f,0.f};

    const int nk = min(q0 + 64, T_LEN);
    const int nit = (nk + 63) >> 6;
    const int srow = tid >> 2;
    const int scol8 = (tid & 3) * 8;

    bf16x8 kreg, vreg;
    {
        int krow = srow; if (krow > T_LEN-1) krow = T_LEN-1;
        const __hip_bfloat16* base = qkv + ((size_t)b*T_LEN + krow)*768 + hh*32 + scol8;
        kreg = *reinterpret_cast<const bf16x8*>(base + 256);
        vreg = *reinterpret_cast<const bf16x8*>(base + 512);
    }

    for (int it = 0; it < nit; ++it) {
        const int bsel = it & 1;
        const int kb = it * 64;
        *reinterpret_cast<bf16x8*>(&Ks[bsel][srow][scol8]) = kreg;
        #pragma unroll
        for (int jj = 0; jj < 8; ++jj) Vt[bsel][scol8 + jj][srow] = vreg[jj];
        __syncthreads();
        if (it + 1 < nit) {
            int krow = kb + 64 + srow; if (krow > T_LEN-1) krow = T_LEN-1;
            const __hip_bfloat16* base = qkv + ((size_t)b*T_LEN + krow)*768 + hh*32 + scol8;
            kreg = *reinterpret_cast<const bf16x8*>(base + 256);
            vreg = *reinterpret_cast<const bf16x8*>(base + 512);
        }

        // QK^T
        f32x4 sc4[4];
        #pragma unroll
        for (int j = 0; j < 4; ++j) {
            bf16x8 bk = *reinterpret_cast<const bf16x8*>(&Ks[bsel][j*16 + c][g*8]);
            sc4[j] = __builtin_amdgcn_mfma_f32_16x16x32_bf16(aq, bk, (f32x4){0.f,0.f,0.f,0.f}, 0, 0, 0);
        }

        // mask + bias
        float sv[4][4];
        #pragma unroll
        for (int j = 0; j < 4; ++j) {
            int kk = kb + j*16 + c;
            #pragma unroll
            for (int rg = 0; rg < 4; ++rg) {
                int qq = qw0 + g*4 + rg;
                bool valid = (qq < T_LEN) && (kk <= qq);
                float s = sc4[j][rg];
                if (ADAPT) s += valid ? hbuf[((size_t)b*T_LEN + qq)*T_LEN + kk] : 0.f;
                sv[j][rg] = valid ? s : -INFINITY;
            }
        }

        // online softmax
        float sf[4];
        #pragma unroll
        for (int rg = 0; rg < 4; ++rg) {
            float m = fmaxf(fmaxf(sv[0][rg], sv[1][rg]), fmaxf(sv[2][rg], sv[3][rg]));
            #pragma unroll
            for (int msk = 1; msk <= 8; msk <<= 1) m = fmaxf(m, __shfl_xor(m, msk));
            float mn = fmaxf(m_r[rg], m);
            sf[rg] = __expf(m_r[rg] - mn);
            m_r[rg] = mn;
        }
        float p[4][4];
        #pragma unroll
        for (int rg = 0; rg < 4; ++rg) {
            float su = 0.f;
            #pragma unroll
            for (int j = 0; j < 4; ++j) {
                float e = __expf(sv[j][rg] - m_r[rg]);
                p[j][rg] = e;
                su += e;
            }
            #pragma unroll
            for (int msk = 1; msk <= 8; msk <<= 1) su += __shfl_xor(su, msk);
            l_r[rg] = l_r[rg] * sf[rg] + su;
            acc[0][rg] *= sf[rg];
            acc[1][rg] *= sf[rg];
        }

        // P -> per-wave LDS
        #pragma unroll
        for (int j = 0; j < 4; ++j)
            #pragma unroll
            for (int rg = 0; rg < 4; ++rg)
                Pw[w][g*4 + rg][j*16 + c] = f2bf_s(p[j][rg]);

        // PV
        #pragma unroll
        for (int kc = 0; kc < 2; ++kc) {
            bf16x8 ap = *reinterpret_cast<const bf16x8*>(&Pw[w][c][kc*32 + g*8]);
            #pragma unroll
            for (int dt = 0; dt < 2; ++dt) {
                bf16x8 bv = *reinterpret_cast<const bf16x8*>(&Vt[bsel][dt*16 + c][kc*32 + g*8]);
                acc[dt] = __builtin_amdgcn_mfma_f32_16x16x32_bf16(ap, bv, acc[dt], 0, 0, 0);
            }
        }
    }

    #pragma unroll
    for (int rg = 0; rg < 4; ++rg) {
        int qq = qw0 + g*4 + rg;
        if (qq >= T_LEN) continue;
        float inv = 1.f / l_r[rg];
        #pragma unroll
        for (int dt = 0; dt < 2; ++dt)
            y[((size_t)b*T_LEN + qq)*256 + hh*32 + dt*16 + c] = __float2bfloat16(acc[dt][rg] * inv);
    }
}

extern "C" void kernel_launch(void* const* d_in, const int* in_sizes, int n_in,
                              void* d_out, int out_size, void* d_ws, size_t ws_size,
                              hipStream_t stream) {
    const float* dc    = (const float*)d_in[0];
    const float* zemb  = (const float*)d_in[1];
    const float* p1    = (const float*)d_in[2];
    const float* p2    = (const float*)d_in[3];
    const float* p3    = (const float*)d_in[4];
    const float* frame = (const float*)d_in[5];
    const float* cam   = (const float*)d_in[6];
    const float* timeE = (const float*)d_in[7];
    const float* locW1 = (const float*)d_in[8];
    const float* locb1 = (const float*)d_in[9];
    const float* locW2 = (const float*)d_in[10];
    const float* locb2 = (const float*)d_in[11];
    const float* ln1w  = (const float*)d_in[12];
    const float* ln1b  = (const float*)d_in[13];
    const float* Wq    = (const float*)d_in[14];
    const float* bq    = (const float*)d_in[15];
    const float* Wk    = (const float*)d_in[16];
    const float* bk    = (const float*)d_in[17];
    const float* Wv    = (const float*)d_in[18];
    const float* bv    = (const float*)d_in[19];
    const float* Wo    = (const float*)d_in[20];
    const float* bo    = (const float*)d_in[21];
    const float* ln2w  = (const float*)d_in[22];
    const float* ln2b  = (const float*)d_in[23];
    const float* W1p   = (const float*)d_in[24];
    const float* b1p   = (const float*)d_in[25];
    const float* W2p   = (const float*)d_in[26];
    const float* b2p   = (const float*)d_in[27];
    const float* lnfw  = (const float*)d_in[28];
    const float* lnfb  = (const float*)d_in[29];
    const float* headW = (const float*)d_in[30];

    char* wsb = (char*)d_ws;
    size_t off = 0;
    auto alloc = [&](size_t bytes) -> char* {
        char* p = wsb + off;
        off += (bytes + 255) & ~(size_t)255;
        return p;
    };
    __hip_bfloat16* wqkv_bf = (__hip_bfloat16*)alloc(12ull*768*256*2);
    float*          bqkv    = (float*)alloc(12ull*768*4);
    __hip_bfloat16* wo_bf = (__hip_bfloat16*)alloc(12ull*65536*2);
    __hip_bfloat16* w1_bf = (__hip_bfloat16*)alloc(12ull*262144*2);
    __hip_bfloat16* w2_bf = (__hip_bfloat16*)alloc(12ull*262144*2);
    __hip_bfloat16* wh_bf = (__hip_bfloat16*)alloc(16384ull*256*2);
    float* hbuf = (float*)alloc(4ull*T_LEN*T_LEN*4);
    float* x    = (float*)alloc((size_t)M_ROWS*256*4);
    __hip_bfloat16* xn   = (__hip_bfloat16*)alloc((size_t)M_ROWS*256*2);
    __hip_bfloat16* qkvb = (__hip_bfloat16*)alloc((size_t)M_ROWS*768*2);
    __hip_bfloat16* yb   = (__hip_bfloat16*)alloc((size_t)M_ROWS*256*2);
    float* z1   = (float*)alloc(720*4);

    // weight prep
    prep_wqkv_kernel<<<(12*768*64 + 255)/256, 256, 0, stream>>>(Wq, Wk, Wv, wqkv_bf);
    prep_bqkv_kernel<<<36, 256, 0, stream>>>(bq, bk, bv, bqkv);
    cvt_kernel<<<768, 256, 0, stream>>>(Wo, wo_bf, 196608);
    cvt_kernel<<<3072, 256, 0, stream>>>(W1p, w1_bf, 786432);
    cvt_kernel<<<3072, 256, 0, stream>>>(W2p, w2_bf, 786432);
    cvt_kernel<<<4096, 256, 0, stream>>>(headW, wh_bf, 1048576);

    // locality bias h
    loc_z1_kernel<<<1, 256, 0, stream>>>(p1, p2, p3, locW1, locb1, z1);
    zero_kernel<<<2048, 256, 0, stream>>>(hbuf, 4*T_LEN*T_LEN);
    h_fill_kernel<<<256, 256, 0, stream>>>(z1, locW2, locb2, hbuf);

    // x init
    init_x_kernel<<<M_ROWS, 256, 0, stream>>>(dc, zemb, frame, cam, timeE, x);

    dim3 gqkv(52, 12);
    dim3 goproj(52, 4);
    dim3 gattn(13, 8, 4);

    for (int i = 0; i < NLAYER; ++i) {
        gemm_k256<true,false,true><<<gqkv, 256, 0, stream>>>(
            x, ln1w + i*256, ln1b + i*256, nullptr,
            wqkv_bf + (size_t)i*196608, bqkv + i*768, nullptr, qkvb, M_ROWS, 768);
        if (i % 2 == 0) attn_mfma_kernel<1><<<gattn, 256, 0, stream>>>(qkvb, hbuf, yb);
        else            attn_mfma_kernel<0><<<gattn, 256, 0, stream>>>(qkvb, hbuf, yb);
        gemm_k256<false,true,false><<<goproj, 256, 0, stream>>>(
            nullptr, nullptr, nullptr, yb,
            wo_bf + (size_t)i*65536, bo + i*256, x, x, M_ROWS, 256);
        if (i == NLAYER-1)
            mlp_fused<true><<<104, 512, 0, stream>>>(
                x, ln2w + i*256, ln2b + i*256,
                w1_bf + (size_t)i*262144, b1p + i*1024,
                w2_bf + (size_t)i*262144, b2p + i*256, lnfw, lnfb, xn);
        else
            mlp_fused<false><<<104, 512, 0, stream>>>(
                x, ln2w + i*256, ln2b + i*256,
                w1_bf + (size_t)i*262144, b1p + i*1024,
                w2_bf + (size_t)i*262144, b2p + i*256, nullptr, nullptr, nullptr);
    }

    // head
    gemm_k256<false,false,false><<<dim3(52, 256), 256, 0, stream>>>(
        nullptr, nullptr, nullptr, xn, wh_bf, nullptr, nullptr, (float*)d_out, M_ROWS, 16384);
}